// Round 2
// baseline (33468.997 us; speedup 1.0000x reference)
//
#include <hip/hip_runtime.h>
#include <hip/hip_bf16.h>
#include <math.h>

// Problem constants
#define T_ 512
#define B_ 128
#define I_ 512
#define H_ 1024

typedef __attribute__((ext_vector_type(8))) short short8;   // 8 x bf16 (4 VGPRs)
typedef __attribute__((ext_vector_type(4))) float floatx4;  // MFMA accumulator

// ---- f32 <-> bf16 split helpers (RNE via integer trick; no NaN in this data) ----
__device__ inline unsigned int f32_to_bf16_rne(float v) {
    unsigned int b = __builtin_bit_cast(unsigned int, v);
    b += 0x7FFFu + ((b >> 16) & 1u);
    return b >> 16;
}
__device__ inline float bf16_to_f32(unsigned int s) {
    unsigned int b = s << 16;
    return __builtin_bit_cast(float, b);
}
// split one f32 into hi+lo bf16 (combined ~16-bit mantissa)
__device__ inline void split1(float v, short& hi, short& lo) {
    unsigned int h = f32_to_bf16_rne(v);
    float r = v - bf16_to_f32(h);
    unsigned int l = f32_to_bf16_rne(r);
    hi = (short)h;
    lo = (short)l;
}

// ---------------- weight split-transpose: f32 [K,N] -> bf16 hi/lo [N,K] ----------------
__global__ void transpose_split_kernel(const float* __restrict__ in, const float* __restrict__ in2,
                                       short* __restrict__ outT_hi, short* __restrict__ outT_lo,
                                       int K, int N) {
    int total = K * N;
    int idx = blockIdx.x * blockDim.x + threadIdx.x;
    int stride = gridDim.x * blockDim.x;
    for (int i = idx; i < total; i += stride) {
        int n = i / K;
        int k = i - n * K;
        float v = in[(size_t)k * N + n];
        if (in2) v += in2[(size_t)k * N + n];
        short h, l;
        split1(v, h, l);
        outT_hi[i] = h;
        outT_lo[i] = l;
    }
}

// ---------------- split GEMM: C[M,N=1024] (=|+=) A[M,K](f32) x BT[N,K](bf16 hi/lo) ----------------
// In-register split of A into hi/lo; 3 MFMAs per 32-wide K-chunk (Ah*Bh + Al*Bh + Ah*Bl).
// Block: 256 threads = 4 waves stacked along M (block tile 64 x 16).
// grid.x = M/64, grid.y = 1024/16. If avg_off > 0, A-value = 0.5*(A[i] + A[i+avg_off]).
__global__ __launch_bounds__(256) void gemm_split_kernel(const float* __restrict__ A,
                                                         const short* __restrict__ BT_hi,
                                                         const short* __restrict__ BT_lo,
                                                         float* __restrict__ C,
                                                         int K, int avg_off, int accumulate) {
    int tid = threadIdx.x;
    int wave = tid >> 6;
    int lane = tid & 63;
    int mbase = blockIdx.x * 64 + wave * 16;
    int nbase = blockIdx.y * 16;

    int arow = mbase + (lane & 15);
    int brow = nbase + (lane & 15);
    int koff = (lane >> 4) * 8;

    const float* ap = A + (size_t)arow * K + koff;
    const short* bph = BT_hi + (size_t)brow * K + koff;
    const short* bpl = BT_lo + (size_t)brow * K + koff;

    floatx4 acc = {0.f, 0.f, 0.f, 0.f};
    for (int k = 0; k < K; k += 32) {
        short8 ah, al, bh, bl;
        bh = *(const short8*)(bph + k);
        bl = *(const short8*)(bpl + k);
        #pragma unroll
        for (int j = 0; j < 8; ++j) {
            float v = ap[k + j];
            if (avg_off) v = 0.5f * (v + ap[k + j + avg_off]);
            short h, l;
            split1(v, h, l);
            ah[j] = h;
            al[j] = l;
        }
        acc = __builtin_amdgcn_mfma_f32_16x16x32_bf16(ah, bh, acc, 0, 0, 0);
        acc = __builtin_amdgcn_mfma_f32_16x16x32_bf16(al, bh, acc, 0, 0, 0);
        acc = __builtin_amdgcn_mfma_f32_16x16x32_bf16(ah, bl, acc, 0, 0, 0);
    }

    int rbase = mbase + ((lane >> 4) << 2);
    int c = nbase + (lane & 15);
    #pragma unroll
    for (int r = 0; r < 4; ++r) {
        size_t idx = (size_t)(rbase + r) * H_ + c;
        if (accumulate) C[idx] += acc[r];
        else            C[idx] = acc[r];
    }
}

// ---------------- recurrence step: out = tanh(pre + hprev @ Wh), all f32 I/O ----------------
// M=128, N=K=1024. grid = (8, 64), 256 threads = 4 waves SPLIT ALONG K (256 each) + LDS reduce.
// hprev == nullptr means h = 0 (first step).
__global__ __launch_bounds__(256) void step_kernel(const float* __restrict__ hprev,
                                                   const short* __restrict__ WhT_hi,
                                                   const short* __restrict__ WhT_lo,
                                                   const float* __restrict__ pre,
                                                   float* __restrict__ outf) {
    __shared__ float red[4][256];
    int tid = threadIdx.x;
    int wave = tid >> 6;
    int lane = tid & 63;
    int mbase = blockIdx.x * 16;
    int nbase = blockIdx.y * 16;

    floatx4 acc = {0.f, 0.f, 0.f, 0.f};
    if (hprev) {
        int arow = mbase + (lane & 15);
        int brow = nbase + (lane & 15);
        int koff = wave * 256 + (lane >> 4) * 8;
        const float* ap = hprev + (size_t)arow * H_ + koff;
        const short* bph = WhT_hi + (size_t)brow * H_ + koff;
        const short* bpl = WhT_lo + (size_t)brow * H_ + koff;
        #pragma unroll
        for (int k = 0; k < 256; k += 32) {
            short8 ah, al, bh, bl;
            bh = *(const short8*)(bph + k);
            bl = *(const short8*)(bpl + k);
            #pragma unroll
            for (int j = 0; j < 8; ++j) {
                short h, l;
                split1(ap[k + j], h, l);
                ah[j] = h;
                al[j] = l;
            }
            acc = __builtin_amdgcn_mfma_f32_16x16x32_bf16(ah, bh, acc, 0, 0, 0);
            acc = __builtin_amdgcn_mfma_f32_16x16x32_bf16(al, bh, acc, 0, 0, 0);
            acc = __builtin_amdgcn_mfma_f32_16x16x32_bf16(ah, bl, acc, 0, 0, 0);
        }
    }

    #pragma unroll
    for (int r = 0; r < 4; ++r)
        red[wave][r * 64 + lane] = acc[r];   // lane-stride-1: conflict-free
    __syncthreads();

    if (tid < 64) {
        int rbase = mbase + ((lane >> 4) << 2);
        int c = nbase + (lane & 15);
        #pragma unroll
        for (int r = 0; r < 4; ++r) {
            float s = red[0][r * 64 + lane] + red[1][r * 64 + lane]
                    + red[2][r * 64 + lane] + red[3][r * 64 + lane];
            size_t idx = (size_t)(rbase + r) * H_ + c;
            outf[idx] = tanhf(pre[idx] + s);
        }
    }
}

// ---------------- launcher ----------------

extern "C" void kernel_launch(void* const* d_in, const int* in_sizes, int n_in,
                              void* d_out, int out_size, void* d_ws, size_t ws_size,
                              hipStream_t stream) {
    const float* x   = (const float*)d_in[0];
    const float* Wi0 = (const float*)d_in[1];
    const float* Wh0 = (const float*)d_in[2];
    const float* Ws0 = (const float*)d_in[3];
    const float* Wi1 = (const float*)d_in[4];
    const float* Wh1 = (const float*)d_in[5];
    const float* Ws1 = (const float*)d_in[6];
    float* out = (float*)d_out;
    char* ws = (char*)d_ws;

    const size_t BH = (size_t)B_ * H_;        // 131072
    const size_t OUT1_OFF = (size_t)T_ * BH;  // start of out1 in d_out

    // workspace layout (bytes); total = 256 MiB pre + 16 MiB weights = 272 MiB
    const size_t MB = 1048576ull;
    float* pre      = (float*)(ws + 0);                  // 512*128*1024 f32 = 256 MiB
    short* W0sumT_h = (short*)(ws + 256 * MB);           // 1024x512  = 1 MiB
    short* W0sumT_l = (short*)(ws + 257 * MB);
    short* Wh0T_h   = (short*)(ws + 258 * MB);           // 1024x1024 = 2 MiB
    short* Wh0T_l   = (short*)(ws + 260 * MB);
    short* Wi1T_h   = (short*)(ws + 262 * MB);
    short* Wi1T_l   = (short*)(ws + 264 * MB);
    short* Wh1T_h   = (short*)(ws + 266 * MB);
    short* Wh1T_l   = (short*)(ws + 268 * MB);
    short* Ws1T_h   = (short*)(ws + 270 * MB);           // 1024x512 = 1 MiB
    short* Ws1T_l   = (short*)(ws + 271 * MB);

    // 1. split-transposed weights
    transpose_split_kernel<<<dim3((I_ * H_ + 255) / 256), 256, 0, stream>>>(Wi0, Ws0, W0sumT_h, W0sumT_l, I_, H_);
    transpose_split_kernel<<<dim3((H_ * H_ + 255) / 256), 256, 0, stream>>>(Wh0, nullptr, Wh0T_h, Wh0T_l, H_, H_);
    transpose_split_kernel<<<dim3((H_ * H_ + 255) / 256), 256, 0, stream>>>(Wi1, nullptr, Wi1T_h, Wi1T_l, H_, H_);
    transpose_split_kernel<<<dim3((H_ * H_ + 255) / 256), 256, 0, stream>>>(Wh1, nullptr, Wh1T_h, Wh1T_l, H_, H_);
    transpose_split_kernel<<<dim3((I_ * H_ + 255) / 256), 256, 0, stream>>>(Ws1, nullptr, Ws1T_h, Ws1T_l, I_, H_);

    // 2. pre0 = x @ (Wi0+Ws0) : M = 65536, K = 512
    gemm_split_kernel<<<dim3(65536 / 64, H_ / 16), 256, 0, stream>>>(
        x, W0sumT_h, W0sumT_l, pre, I_, 0, 0);

    // 3. layer-0 recurrence: out0[t] = tanh(pre[t] + out0[t-1] @ Wh0); state read from d_out (f32)
    for (int t = 0; t < T_; ++t) {
        const float* hp = (t == 0) ? nullptr : (out + (size_t)(t - 1) * BH);
        step_kernel<<<dim3(8, H_ / 16), 256, 0, stream>>>(
            hp, Wh0T_h, Wh0T_l, pre + (size_t)t * BH, out + (size_t)t * BH);
    }

    // 4. pre1 = out0[1:] @ Wi1 + sx1 @ Ws1 : M = 511*128 = 65408
    gemm_split_kernel<<<dim3(65408 / 64, H_ / 16), 256, 0, stream>>>(
        out + BH, Wi1T_h, Wi1T_l, pre, H_, 0, 0);
    gemm_split_kernel<<<dim3(65408 / 64, H_ / 16), 256, 0, stream>>>(
        x, Ws1T_h, Ws1T_l, pre, I_, B_ * I_, 1);

    // 5. layer-1 recurrence
    for (int t = 0; t < T_ - 1; ++t) {
        const float* hp = (t == 0) ? nullptr : (out + OUT1_OFF + (size_t)(t - 1) * BH);
        step_kernel<<<dim3(8, H_ / 16), 256, 0, stream>>>(
            hp, Wh1T_h, Wh1T_l, pre + (size_t)t * BH, out + OUT1_OFF + (size_t)t * BH);
    }
}